// Round 6
// baseline (292.840 us; speedup 1.0000x reference)
//
#include <hip/hip_runtime.h>

// 32 planes of 1024x1024 f32: 5x5 box blur (SAME, zero-pad) -> data-dependent
// threshold (quantile over exact f32 cascade T[k]=T[k-1]-0.0005f) -> binarize
// -> morphological close (5x5 dilate, 5x5 erode) -> f32 0/1 output.
//
// Round 10 (= round 9 with the nontemporal-store type fixed: the builtin
// needs a native ext_vector_type pointer, not HIP_vector_type).
// Phase-A upgrades vs round 7:
//  - Neighbor columns via wave shuffle: B-stream running sums (cols
//    4t+4..4t+7) == thread t+1's cs0..3 -> 4 x __shfl_down per row. Only
//    wlane==63 lanes keep a private B-column stream (neighbor in next wave;
//    tid 255 wraps to cols 0..3). Halves loads+cvts for 63/64 lanes.
//  - 2-read find_ki: guess biased +0.5 -> floor in {k-1,k} (err <=0.063
//    step << 0.438 slack) -> k = lo + (s<Us[lo]) + (s<Us[lo+1]).
//  - __launch_bounds__(256,8): round-3 occupancy sat at the declared
//    4 waves/EU floor; raise to 8 (VGPR cap 64, est. live ~55).
//  - k_post: nontemporal output stores (128MB stream, keep L2 for kq/x).

#define K_STEPS 1024
#define LO_COUNT 28185723u     // ceil(0.84 * 2^25)
#define R_TILE 16              // pass1 rows per block -> 64x32 = 2048 blocks
#define PT_ROWS 16             // post rows per block  -> 64x32 = 2048 blocks

// ws: (unused)[4096] @0 ; hist[1025] @4096 ; kq u8[2^25] @16384 (32MB)
#define OFF_HIST 4096
#define OFF_KQ   16384

typedef float  fx4 __attribute__((ext_vector_type(4)));

struct TTable { float v[K_STEPS]; };
static constexpr TTable make_T() {
    TTable t{};
    float th = 0.5f;                          // TH1_INIT; exact f32 cascade
    for (int k = 0; k < K_STEPS; k++) { t.v[k] = th; th = th - 0.0005f; }
    return t;
}
__device__ constexpr TTable Tc = make_T();

__device__ __forceinline__ uint4 cvt4(float4 f) {
    // x in [0,1) is a multiple of 2^-23 -> x*2^23 is an exact integer in f32
    return make_uint4((unsigned int)(f.x * 8388608.0f),
                      (unsigned int)(f.y * 8388608.0f),
                      (unsigned int)(f.z * 8388608.0f),
                      (unsigned int)(f.w * 8388608.0f));
}

// smallest k with s >= Us[k] (Us non-increasing staircase, ~104857.6 s-units
// per step). Cascade drift <= 1024*2^-25 = 0.061 step; f32 guess arithmetic
// (values < 2^28, fma) <= ~2e-4 step. For s in [U[k],U[k-1]): g in
// (k-1.062, k+0.062]; +0.5 bias -> g' in (k-0.562, k+0.562] -> floor(g') in
// {k-1, k} -> window {lo, lo+1} contains k; indicator sum is exact:
//   lo=k-1: s<Us[k-1] (+1), s>=Us[k] (+0) -> k.   lo=k: both >= -> k.
// s >= U0 (k=0): g' < 0.562 -> lo=0, indicators 0 -> 0. s=0: g'~1000.5 ->
// lo=1000, U[1000]=1 (+1), U[1001]=0 (+0) -> 1001 (= first zero bin).
__device__ __forceinline__ int find_ki(const unsigned int* __restrict__ Us,
                                       float gbias, unsigned int s) {
    float g = fmaf(-(float)s, 9.5367432e-6f, gbias);   // gbias = U0*inv + 0.5
    int lo = (int)g;
    lo = max(0, min(1022, lo));
    unsigned int a0 = Us[lo], a1 = Us[lo + 1];
    return lo + (int)(s < a0) + (int)(s < a1);
}

// Pass 1: 16-row strip per block. Thread t owns cols 4t..4t+3 running sums
// (rows y-2..y+2); neighbor sums come from lane t+1 via __shfl_down; edge
// lanes (wlane==63) keep a private neighbor stream (tid 255 wraps to cols
// 0..3). Outputs cols 4t+2..4t+5 (tid 255: 1022,1023,0,1). Two prefetch
// streams (incoming y+3 two-deep, departing y-2 two-deep; edge B-streams
// one-deep). k==0 (~50% of px) counted in a register; LDS atomics only for
// k>0. Aligned u32 kq stores via shfl.
__global__ __launch_bounds__(256, 8) void
k_pass1(const float4* __restrict__ x4, const float* __restrict__ bk,
        unsigned int* __restrict__ hist, unsigned short* __restrict__ kq16) {
    __shared__ unsigned int Us[K_STEPS];
    __shared__ unsigned int lh[K_STEPS + 1];
    int tid = threadIdx.x;
    int p = blockIdx.y, y0 = blockIdx.x * R_TILE;
    int wlane = tid & 63;

    {   // Build U table: U[k] = min{u : u*c > T[k]} exactly.
        // u < 2^27, c = w*2^-23 (24-bit mantissa) -> u*c exact in double.
        double c = (double)bk[0] * (1.0 / 8388608.0);
        #pragma unroll
        for (int i = 0; i < 4; i++) {
            int k = tid + 256 * i;
            double T = (double)Tc.v[k];
            unsigned int u = 0u;
            if (T >= 0.0) {
                u = (unsigned int)(floor(T / c) + 1.0);
                while (u > 0u && (double)(u - 1u) * c > T) u--;
                while (!((double)u * c > T)) u++;
            }
            Us[k] = u;
        }
    }
    for (int i = tid; i < K_STEPS + 1; i += 256) lh[i] = 0u;
    __syncthreads();
    float gbias = fmaf((float)Us[0], 9.5367432e-6f, 0.5f);

    const float4* pf = x4 + (size_t)p * 262144;   // 256 float4 per row
    int tB = (tid < 255) ? tid + 1 : 0;
    const uint4 z4 = make_uint4(0u, 0u, 0u, 0u);
    bool edge = (wlane == 63);

    unsigned int cs0 = 0, cs1 = 0, cs2 = 0, cs3 = 0;
    unsigned int cb0 = 0, cb1 = 0, cb2 = 0, cb3 = 0;  // edge lanes only
    {
        float4 ra[5], rb[5];
        #pragma unroll
        for (int i = 0; i < 5; i++) {
            int yy = y0 - 2 + i, yc = min(max(yy, 0), 1023);
            ra[i] = pf[yc * 256 + tid];
            if (edge) rb[i] = pf[yc * 256 + tB];
        }
        #pragma unroll
        for (int i = 0; i < 5; i++) {
            bool v = (unsigned)(y0 - 2 + i) < 1024u;
            uint4 a = v ? cvt4(ra[i]) : z4;
            cs0 += a.x; cs1 += a.y; cs2 += a.z; cs3 += a.w;
            if (edge) {
                uint4 b = v ? cvt4(rb[i]) : z4;
                cb0 += b.x; cb1 += b.y; cb2 += b.z; cb3 += b.w;
            }
        }
    }
    // A-stream prefetch, 2 deep: N = incoming row (y+3), O = departing (y-2).
    // Edge B-streams, 1 deep.
    float4 N0a, N1a, O0a, O1a, NBa, OBa;
    {
        int yn0 = min(y0 + 3, 1023), yn1 = min(y0 + 4, 1023);
        int yo0 = max(y0 - 2, 0),    yo1 = max(y0 - 1, 0);
        N0a = pf[yn0 * 256 + tid]; N1a = pf[yn1 * 256 + tid];
        O0a = pf[yo0 * 256 + tid]; O1a = pf[yo1 * 256 + tid];
        if (edge) { NBa = pf[yn0 * 256 + tB]; OBa = pf[yo0 * 256 + tB]; }
    }

    unsigned int cnt0 = 0;
    #pragma unroll 4
    for (int iy = 0; iy < R_TILE; iy++) {
        int y = y0 + iy;

        // neighbor sums (cols 4t+4..4t+7) via shuffle; edge lanes override
        unsigned int nc0 = __shfl_down(cs0, 1);
        unsigned int nc1 = __shfl_down(cs1, 1);
        unsigned int nc2 = __shfl_down(cs2, 1);
        unsigned int nc3 = __shfl_down(cs3, 1);
        if (edge) { nc0 = cb0; nc1 = cb1; nc2 = cb2; nc3 = cb3; }

        unsigned int m123 = cs1 + cs2 + cs3;
        unsigned int h45  = nc0 + nc1;
        unsigned int v0, v1, v2, v3;
        if (tid != 255) {
            v0 = cs0 + m123 + nc0;                // col 4t+2
            v1 = m123 + h45;                      // col 4t+3
            v2 = cs2 + cs3 + h45 + nc2;           // col 4t+4
            v3 = cs3 + h45 + nc2 + nc3;           // col 4t+5
        } else {
            v0 = cs0 + m123;                      // col 1022 (cols 1020..1023)
            v1 = m123;                            // col 1023 (cols 1021..1023)
            v2 = h45 + nc2;                       // col 0    (cols 0..2)
            v3 = h45 + nc2 + nc3;                 // col 1    (cols 0..3)
        }

        int k0 = find_ki(Us, gbias, v0);
        int k1 = find_ki(Us, gbias, v1);
        int k2 = find_ki(Us, gbias, v2);
        int k3 = find_ki(Us, gbias, v3);
        cnt0 += (unsigned)(k0 == 0) + (unsigned)(k1 == 0)
              + (unsigned)(k2 == 0) + (unsigned)(k3 == 0);
        if (k0 > 0) atomicAdd(&lh[k0], 1u);
        if (k1 > 0) atomicAdd(&lh[k1], 1u);
        if (k2 > 0) atomicAdd(&lh[k2], 1u);
        if (k3 > 0) atomicAdd(&lh[k3], 1u);

        // pack + aligned coalesced store. Word w = cols 4w..4w+3.
        // word(t+1) = pb(t) | pa(t+1)<<16 (wlane<63 via shfl); words 64w:
        // low half = pb of wlane==63 (u16 at 2t+2; tid 255 -> u16 0),
        // high half = pa of wlane==0 (u16 at 2t+1).
        unsigned int pa = (unsigned)min(k0, 255) | ((unsigned)min(k1, 255) << 8);
        unsigned int pb = (unsigned)min(k2, 255) | ((unsigned)min(k3, 255) << 8);
        unsigned int paN = __shfl_down(pa, 1);
        size_t rb = ((size_t)p * 1024 + (size_t)y) * 512;   // u16 units
        if (wlane < 63) {
            ((unsigned int*)(kq16 + rb))[tid + 1] = pb | (paN << 16);
        } else {
            kq16[rb + ((tid < 255) ? (unsigned)(2 * tid + 2) : 0u)] =
                (unsigned short)pb;
        }
        if (wlane == 0) kq16[rb + 2 * tid + 1] = (unsigned short)pa;

        // running-sum update: += row(y+3), -= row(y-2) (exact u32)
        {
            bool vn = (unsigned)(y + 3) < 1024u;
            bool vo = (y - 2) >= 0;
            uint4 na = vn ? cvt4(N0a) : z4;
            uint4 oa = vo ? cvt4(O0a) : z4;
            cs0 += na.x - oa.x; cs1 += na.y - oa.y;
            cs2 += na.z - oa.z; cs3 += na.w - oa.w;
            if (edge) {
                uint4 nb = vn ? cvt4(NBa) : z4;
                uint4 ob = vo ? cvt4(OBa) : z4;
                cb0 += nb.x - ob.x; cb1 += nb.y - ob.y;
                cb2 += nb.z - ob.z; cb3 += nb.w - ob.w;
            }
        }
        // rotate prefetch; refill A 2 ahead (iter iy+2: +row y+5, -row y),
        // edge B-streams 1 ahead (iter iy+1: +row y+4, -row y-1).
        N0a = N1a; O0a = O1a;
        {
            int yn = min(y + 5, 1023);
            N1a = pf[yn * 256 + tid];
            O1a = pf[y * 256 + tid];
            if (edge) {
                int ynb = min(y + 4, 1023), yob = max(y - 1, 0);
                NBa = pf[ynb * 256 + tB];
                OBa = pf[yob * 256 + tB];
            }
        }
    }

    #pragma unroll
    for (int d = 32; d > 0; d >>= 1) cnt0 += __shfl_down(cnt0, d);
    if ((tid & 63) == 0 && cnt0) atomicAdd(&lh[0], cnt0);
    __syncthreads();
    for (int i = tid; i < K_STEPS + 1; i += 256) {
        unsigned int c = lh[i];
        if (c) atomicAdd(&hist[i], c);
    }
}

// Fused post: in-block solve -> binarize (k<=ks) -> dilate -> erode -> f32
// unpack. 16-row tile per block, bit-packed intermediates in LDS.
// Loop 2 of the reference (frac > 0.86) cannot trigger: it needs a single
// 0.0005-wide bin holding >= 671089 px; max possible ~115k.
__global__ __launch_bounds__(256) void
k_post(const unsigned char* __restrict__ kqb, const unsigned int* __restrict__ hist,
       float* __restrict__ out) {
    __shared__ unsigned long long Tt[24 * 16];  // thr rows y0-4 .. y0+19
    __shared__ unsigned long long Vv[20 * 16];  // vertical OR, rows y0-2 .. y0+17
    __shared__ unsigned long long Dd[20 * 16];  // dilated,     rows y0-2 .. y0+17
    __shared__ unsigned long long Ww[16 * 16];  // vertical AND, rows y0 .. y0+15
    __shared__ unsigned long long Ff[16 * 16];  // closed bits
    __shared__ int ksS;

    int tid = threadIdx.x;
    int p = blockIdx.y, y0 = blockIdx.x * PT_ROWS;

    // Phase 0: solve (wave 0 only), redundant per block — removes a launch.
    if (tid < 64) {
        int lane = tid;
        unsigned int h[16], s = 0;
        #pragma unroll
        for (int i = 0; i < 16; i++) { h[i] = hist[lane * 16 + i]; s += h[i]; }
        unsigned int inc = s;
        #pragma unroll
        for (int d = 1; d < 64; d <<= 1) {
            unsigned int t = __shfl_up(inc, d);
            if (lane >= d) inc += t;
        }
        unsigned int excl = inc - s;
        bool cross = (excl < LO_COUNT) && (excl + s >= LO_COUNT);
        unsigned long long m = __ballot(cross);
        if (m) {
            int cl = __ffsll((long long)m) - 1;
            if (lane == cl) {
                unsigned int c = excl; int ks = K_STEPS - 1;
                for (int i = 0; i < 16; i++) { c += h[i]; if (c >= LO_COUNT) { ks = lane * 16 + i; break; } }
                ksS = ks;
            }
        } else if (lane == 0) ksS = K_STEPS - 1;
    }
    __syncthreads();
    int ks = ksS;

    // Phase 1: threshold bits. Each thread: 6 x (uint4 load of 16 kq bytes ->
    // 16-bit mask -> u16 LDS write). 24 rows x 64 chunks = 1536 chunks.
    const unsigned char* kp = kqb + (size_t)p * 1048576;
    unsigned short* Tt16 = (unsigned short*)Tt;
    #pragma unroll
    for (int i = 0; i < 6; i++) {
        int ch = tid + 256 * i;             // 0..1535
        int r = ch >> 6, cc = ch & 63;
        int pr = y0 - 4 + r;
        unsigned int m = 0u;
        if ((unsigned)pr < 1024u) {
            uint4 q = ((const uint4*)(kp + (size_t)pr * 1024))[cc];
            unsigned int wv;
            wv = q.x;
            m |= (unsigned)((wv & 0xffu) <= (unsigned)ks)
               | ((unsigned)(((wv >> 8) & 0xffu) <= (unsigned)ks) << 1)
               | ((unsigned)(((wv >> 16) & 0xffu) <= (unsigned)ks) << 2)
               | ((unsigned)((wv >> 24) <= (unsigned)ks) << 3);
            wv = q.y;
            m |= ((unsigned)((wv & 0xffu) <= (unsigned)ks) << 4)
               | ((unsigned)(((wv >> 8) & 0xffu) <= (unsigned)ks) << 5)
               | ((unsigned)(((wv >> 16) & 0xffu) <= (unsigned)ks) << 6)
               | ((unsigned)((wv >> 24) <= (unsigned)ks) << 7);
            wv = q.z;
            m |= ((unsigned)((wv & 0xffu) <= (unsigned)ks) << 8)
               | ((unsigned)(((wv >> 8) & 0xffu) <= (unsigned)ks) << 9)
               | ((unsigned)(((wv >> 16) & 0xffu) <= (unsigned)ks) << 10)
               | ((unsigned)((wv >> 24) <= (unsigned)ks) << 11);
            wv = q.w;
            m |= ((unsigned)((wv & 0xffu) <= (unsigned)ks) << 12)
               | ((unsigned)(((wv >> 8) & 0xffu) <= (unsigned)ks) << 13)
               | ((unsigned)(((wv >> 16) & 0xffu) <= (unsigned)ks) << 14)
               | ((unsigned)((wv >> 24) <= (unsigned)ks) << 15);
        }
        Tt16[ch] = (unsigned short)m;
    }
    __syncthreads();

    // Phase 2: vertical OR of 5 thr rows (20 rows x 16 words = 320)
    for (int i = tid; i < 320; i += 256) {
        int vr = i >> 4, wc = i & 15;
        int b = vr * 16 + wc;
        Vv[i] = Tt[b] | Tt[b + 16] | Tt[b + 32] | Tt[b + 48] | Tt[b + 64];
    }
    __syncthreads();

    // Phase 3: horizontal dilate; rows outside the plane forced to all-ones
    // (erode identity — erosion ignores out-of-image rows).
    for (int i = tid; i < 320; i += 256) {
        int vr = i >> 4, wc = i & 15;
        int pr = y0 - 2 + vr;
        if ((unsigned)pr >= 1024u) { Dd[i] = ~0ull; continue; }
        unsigned long long Vc = Vv[i];
        unsigned long long Vl = (wc > 0)  ? Vv[i - 1] : 0ull;
        unsigned long long Vr = (wc < 15) ? Vv[i + 1] : 0ull;
        Dd[i] = Vc
            | (Vc << 1) | (Vl >> 63)
            | (Vc << 2) | (Vl >> 62)
            | (Vc >> 1) | (Vr << 63)
            | (Vc >> 2) | (Vr << 62);
    }
    __syncthreads();

    // Phase 4: vertical AND of 5 dilated rows (16 x 16 = 256)
    {
        int wr = tid >> 4, wc = tid & 15;
        int b = wr * 16 + wc;
        Ww[tid] = Dd[b] & Dd[b + 16] & Dd[b + 32] & Dd[b + 48] & Dd[b + 64];
    }
    __syncthreads();

    // Phase 5: horizontal erode (outside cols = 1)
    {
        int wc = tid & 15;
        unsigned long long Wc = Ww[tid];
        unsigned long long Wl = (wc > 0)  ? Ww[tid - 1] : ~0ull;
        unsigned long long Wr = (wc < 15) ? Ww[tid + 1] : ~0ull;
        Ff[tid] = Wc
            & ((Wc << 1) | (Wl >> 63))
            & ((Wc << 2) | (Wl >> 62))
            & ((Wc >> 1) | (Wr << 63))
            & ((Wc >> 2) | (Wr << 62));
    }
    __syncthreads();

    // Phase 6: unpack to f32, nontemporal coalesced 16B stores
    for (int i = 0; i < PT_ROWS; i++) {
        unsigned long long wd = Ff[i * 16 + (tid >> 4)];
        int sh = (tid & 15) * 4;
        fx4 f;
        f.x = (float)((wd >> sh) & 1ull);
        f.y = (float)((wd >> (sh + 1)) & 1ull);
        f.z = (float)((wd >> (sh + 2)) & 1ull);
        f.w = (float)((wd >> (sh + 3)) & 1ull);
        fx4* dst = (fx4*)(out + (size_t)p * 1048576 + (size_t)(y0 + i) * 1024) + tid;
        __builtin_nontemporal_store(f, dst);
    }
}

extern "C" void kernel_launch(void* const* d_in, const int* in_sizes, int n_in,
                              void* d_out, int out_size, void* d_ws, size_t ws_size,
                              hipStream_t stream) {
    const float4* x4 = (const float4*)d_in[0];
    const float*  bk = (const float*)d_in[1];
    float* out = (float*)d_out;

    char* ws = (char*)d_ws;
    unsigned int*   hist = (unsigned int*)(ws + OFF_HIST);
    unsigned short* kq16 = (unsigned short*)(ws + OFF_KQ);
    const unsigned char* kqb = (const unsigned char*)(ws + OFF_KQ);

    (void)hipMemsetAsync(hist, 0, (K_STEPS + 1) * sizeof(unsigned int), stream);

    dim3 g1(1024 / R_TILE, 32);
    k_pass1<<<g1, 256, 0, stream>>>(x4, bk, hist, kq16);

    dim3 g2(1024 / PT_ROWS, 32);
    k_post<<<g2, 256, 0, stream>>>(kqb, hist, out);
}

// Round 8
// 289.074 us; speedup vs baseline: 1.0130x; 1.0130x over previous
//
#include <hip/hip_runtime.h>

// 32 planes of 1024x1024 f32: 5x5 box blur (SAME, zero-pad) -> data-dependent
// threshold (quantile over exact f32 cascade T[k]=T[k-1]-0.0005f) -> binarize
// -> morphological close (5x5 dilate, 5x5 erode) -> f32 0/1 output.
//
// Round 12 (= round 11 with the k_post halo bug fixed: a zero-filled kq
// chunk binarizes to ONES (k=0 <= ks), so out-of-plane rows must be masked
// AFTER the byte compares, not zero-filled at load).
//  - pass1: high-TLP, no cross-iteration register prefetch (rounds 1/2/6:
//    the allocator sinks/spills multi-deep float4 pipelines). Per row:
//    issue loads (y+3, y-2) -> compute from current running sums -> retire.
//    __launch_bounds__(256,6).
//  - k_post: kq loads hoisted above the Phase-0 solve (solve runs under kq
//    load latency); __launch_bounds__(256,6); nontemporal output stores.

#define K_STEPS 1024
#define LO_COUNT 28185723u     // ceil(0.84 * 2^25)
#define R_TILE 16              // pass1 rows per block -> 64x32 = 2048 blocks
#define PT_ROWS 16             // post rows per block  -> 64x32 = 2048 blocks

// ws: (unused)[4096] @0 ; hist[1025] @4096 ; kq u8[2^25] @16384 (32MB)
#define OFF_HIST 4096
#define OFF_KQ   16384

typedef float  fx4 __attribute__((ext_vector_type(4)));

struct TTable { float v[K_STEPS]; };
static constexpr TTable make_T() {
    TTable t{};
    float th = 0.5f;                          // TH1_INIT; exact f32 cascade
    for (int k = 0; k < K_STEPS; k++) { t.v[k] = th; th = th - 0.0005f; }
    return t;
}
__device__ constexpr TTable Tc = make_T();

__device__ __forceinline__ uint4 cvt4(float4 f) {
    // x in [0,1) is a multiple of 2^-23 -> x*2^23 is an exact integer in f32
    return make_uint4((unsigned int)(f.x * 8388608.0f),
                      (unsigned int)(f.y * 8388608.0f),
                      (unsigned int)(f.z * 8388608.0f),
                      (unsigned int)(f.w * 8388608.0f));
}

// smallest k with s >= Us[k] (Us non-increasing staircase, ~104857.6 s-units
// per step). Cascade drift <= 1024*2^-25 = 0.061 step; f32 guess arithmetic
// (values < 2^28, fma) <= ~2e-4 step. For s in [U[k],U[k-1]): g in
// (k-1.062, k+0.062]; +0.5 bias -> g' in (k-0.562, k+0.562] -> floor(g') in
// {k-1, k} -> window {lo, lo+1} contains k; indicator sum is exact:
//   lo=k-1: s<Us[k-1] (+1), s>=Us[k] (+0) -> k.   lo=k: both >= -> k.
// s >= U0 (k=0): g' < 0.562 -> lo=0, indicators 0 -> 0. s=0: g'~1000.5 ->
// lo=1000, U[1000]=1 (+1), U[1001]=0 (+0) -> 1001 (= first zero bin).
__device__ __forceinline__ int find_ki(const unsigned int* __restrict__ Us,
                                       float gbias, unsigned int s) {
    float g = fmaf(-(float)s, 9.5367432e-6f, gbias);   // gbias = U0*inv + 0.5
    int lo = (int)g;
    lo = max(0, min(1022, lo));
    unsigned int a0 = Us[lo], a1 = Us[lo + 1];
    return lo + (int)(s < a0) + (int)(s < a1);
}

// Pass 1: 16-row strip per block. Thread t owns cols 4t..4t+3 running sums
// (rows y-2..y+2); neighbor sums from lane t+1 via __shfl_down; edge lanes
// (wlane==63) keep a private neighbor stream (tid 255 wraps to cols 0..3).
// Outputs cols 4t+2..4t+5 (tid 255: 1022,1023,0,1). Per iteration:
// issue loads -> compute (hides latency) -> retire into running sums.
// k==0 (~50% of px) counted in a register; LDS atomics only for k>0.
__global__ __launch_bounds__(256, 6) void
k_pass1(const float4* __restrict__ x4, const float* __restrict__ bk,
        unsigned int* __restrict__ hist, unsigned short* __restrict__ kq16) {
    __shared__ unsigned int Us[K_STEPS];
    __shared__ unsigned int lh[K_STEPS + 1];
    int tid = threadIdx.x;
    int p = blockIdx.y, y0 = blockIdx.x * R_TILE;
    int wlane = tid & 63;

    {   // Build U table: U[k] = min{u : u*c > T[k]} exactly.
        // u < 2^27, c = w*2^-23 (24-bit mantissa) -> u*c exact in double.
        double c = (double)bk[0] * (1.0 / 8388608.0);
        #pragma unroll
        for (int i = 0; i < 4; i++) {
            int k = tid + 256 * i;
            double T = (double)Tc.v[k];
            unsigned int u = 0u;
            if (T >= 0.0) {
                u = (unsigned int)(floor(T / c) + 1.0);
                while (u > 0u && (double)(u - 1u) * c > T) u--;
                while (!((double)u * c > T)) u++;
            }
            Us[k] = u;
        }
    }
    for (int i = tid; i < K_STEPS + 1; i += 256) lh[i] = 0u;
    __syncthreads();
    float gbias = fmaf((float)Us[0], 9.5367432e-6f, 0.5f);

    const float4* pf = x4 + (size_t)p * 262144;   // 256 float4 per row
    int tB = (tid < 255) ? tid + 1 : 0;
    const uint4 z4 = make_uint4(0u, 0u, 0u, 0u);
    bool edge = (wlane == 63);

    unsigned int cs0 = 0, cs1 = 0, cs2 = 0, cs3 = 0;
    unsigned int cb0 = 0, cb1 = 0, cb2 = 0, cb3 = 0;  // edge lanes only
    {
        float4 ra[5], rb[5];
        #pragma unroll
        for (int i = 0; i < 5; i++) {
            int yy = y0 - 2 + i, yc = min(max(yy, 0), 1023);
            ra[i] = pf[yc * 256 + tid];
            if (edge) rb[i] = pf[yc * 256 + tB];
        }
        #pragma unroll
        for (int i = 0; i < 5; i++) {
            bool v = (unsigned)(y0 - 2 + i) < 1024u;
            uint4 a = v ? cvt4(ra[i]) : z4;
            cs0 += a.x; cs1 += a.y; cs2 += a.z; cs3 += a.w;
            if (edge) {
                uint4 b = v ? cvt4(rb[i]) : z4;
                cb0 += b.x; cb1 += b.y; cb2 += b.z; cb3 += b.w;
            }
        }
    }

    unsigned int cnt0 = 0;
    #pragma unroll 4
    for (int iy = 0; iy < R_TILE; iy++) {
        int y = y0 + iy;

        // (1) ISSUE this row's incoming/departing loads (clamped addresses;
        // validity handled at retire). No loop-carried prefetch registers.
        int yn = min(y + 3, 1023), yo = max(y - 2, 0);
        float4 Na = pf[yn * 256 + tid];
        float4 Oa = pf[yo * 256 + tid];
        float4 Nb, Ob;
        if (edge) { Nb = pf[yn * 256 + tB]; Ob = pf[yo * 256 + tB]; }

        // (2) COMPUTE from current running sums (independent of the loads
        // above -> their latency hides under this).
        unsigned int nc0 = __shfl_down(cs0, 1);
        unsigned int nc1 = __shfl_down(cs1, 1);
        unsigned int nc2 = __shfl_down(cs2, 1);
        unsigned int nc3 = __shfl_down(cs3, 1);
        if (edge) { nc0 = cb0; nc1 = cb1; nc2 = cb2; nc3 = cb3; }

        unsigned int m123 = cs1 + cs2 + cs3;
        unsigned int h45  = nc0 + nc1;
        unsigned int v0, v1, v2, v3;
        if (tid != 255) {
            v0 = cs0 + m123 + nc0;                // col 4t+2
            v1 = m123 + h45;                      // col 4t+3
            v2 = cs2 + cs3 + h45 + nc2;           // col 4t+4
            v3 = cs3 + h45 + nc2 + nc3;           // col 4t+5
        } else {
            v0 = cs0 + m123;                      // col 1022 (cols 1020..1023)
            v1 = m123;                            // col 1023 (cols 1021..1023)
            v2 = h45 + nc2;                       // col 0    (cols 0..2)
            v3 = h45 + nc2 + nc3;                 // col 1    (cols 0..3)
        }

        int k0 = find_ki(Us, gbias, v0);
        int k1 = find_ki(Us, gbias, v1);
        int k2 = find_ki(Us, gbias, v2);
        int k3 = find_ki(Us, gbias, v3);
        cnt0 += (unsigned)(k0 == 0) + (unsigned)(k1 == 0)
              + (unsigned)(k2 == 0) + (unsigned)(k3 == 0);
        if (k0 > 0) atomicAdd(&lh[k0], 1u);
        if (k1 > 0) atomicAdd(&lh[k1], 1u);
        if (k2 > 0) atomicAdd(&lh[k2], 1u);
        if (k3 > 0) atomicAdd(&lh[k3], 1u);

        // pack + aligned coalesced store. Word w = cols 4w..4w+3.
        // word(t+1) = pb(t) | pa(t+1)<<16 (wlane<63 via shfl); words 64w:
        // low half = pb of wlane==63 (u16 at 2t+2; tid 255 -> u16 0),
        // high half = pa of wlane==0 (u16 at 2t+1).
        unsigned int pa = (unsigned)min(k0, 255) | ((unsigned)min(k1, 255) << 8);
        unsigned int pb = (unsigned)min(k2, 255) | ((unsigned)min(k3, 255) << 8);
        unsigned int paN = __shfl_down(pa, 1);
        size_t rb = ((size_t)p * 1024 + (size_t)y) * 512;   // u16 units
        if (wlane < 63) {
            ((unsigned int*)(kq16 + rb))[tid + 1] = pb | (paN << 16);
        } else {
            kq16[rb + ((tid < 255) ? (unsigned)(2 * tid + 2) : 0u)] =
                (unsigned short)pb;
        }
        if (wlane == 0) kq16[rb + 2 * tid + 1] = (unsigned short)pa;

        // (3) RETIRE: += row(y+3), -= row(y-2) (exact u32)
        {
            bool vn = (unsigned)(y + 3) < 1024u;
            bool vo = (y - 2) >= 0;
            uint4 na = vn ? cvt4(Na) : z4;
            uint4 oa = vo ? cvt4(Oa) : z4;
            cs0 += na.x - oa.x; cs1 += na.y - oa.y;
            cs2 += na.z - oa.z; cs3 += na.w - oa.w;
            if (edge) {
                uint4 nb = vn ? cvt4(Nb) : z4;
                uint4 ob = vo ? cvt4(Ob) : z4;
                cb0 += nb.x - ob.x; cb1 += nb.y - ob.y;
                cb2 += nb.z - ob.z; cb3 += nb.w - ob.w;
            }
        }
    }

    #pragma unroll
    for (int d = 32; d > 0; d >>= 1) cnt0 += __shfl_down(cnt0, d);
    if ((tid & 63) == 0 && cnt0) atomicAdd(&lh[0], cnt0);
    __syncthreads();
    for (int i = tid; i < K_STEPS + 1; i += 256) {
        unsigned int c = lh[i];
        if (c) atomicAdd(&hist[i], c);
    }
}

// Fused post: in-block solve -> binarize (k<=ks) -> dilate -> erode -> f32
// unpack. 16-row tile per block, bit-packed intermediates in LDS. kq loads
// hoisted ABOVE the solve so hist-read latency and kq-read latency overlap.
// Out-of-plane rows are masked to 0 AFTER the byte compares (a zero byte
// binarizes to 1 — round-7 bug).
// Loop 2 of the reference (frac > 0.86) cannot trigger: it needs a single
// 0.0005-wide bin holding >= 671089 px; max possible ~115k.
__global__ __launch_bounds__(256, 6) void
k_post(const unsigned char* __restrict__ kqb, const unsigned int* __restrict__ hist,
       float* __restrict__ out) {
    __shared__ unsigned long long Tt[24 * 16];  // thr rows y0-4 .. y0+19
    __shared__ unsigned long long Vv[20 * 16];  // vertical OR, rows y0-2 .. y0+17
    __shared__ unsigned long long Dd[20 * 16];  // dilated,     rows y0-2 .. y0+17
    __shared__ unsigned long long Ww[16 * 16];  // vertical AND, rows y0 .. y0+15
    __shared__ unsigned long long Ff[16 * 16];  // closed bits
    __shared__ int ksS;

    int tid = threadIdx.x;
    int p = blockIdx.y, y0 = blockIdx.x * PT_ROWS;

    // Phase -1: ISSUE all six kq chunk loads (independent of ks).
    const unsigned char* kp = kqb + (size_t)p * 1048576;
    uint4 q0, q1, q2, q3, q4, q5;
    {
        const uint4 zq = make_uint4(0u, 0u, 0u, 0u);
        #pragma unroll
        for (int i = 0; i < 6; i++) {
            int ch = tid + 256 * i;         // 0..1535
            int r = ch >> 6, cc = ch & 63;
            int pr = y0 - 4 + r;
            uint4 q = zq;
            if ((unsigned)pr < 1024u)
                q = ((const uint4*)(kp + (size_t)pr * 1024))[cc];
            if (i == 0) q0 = q; else if (i == 1) q1 = q;
            else if (i == 2) q2 = q; else if (i == 3) q3 = q;
            else if (i == 4) q4 = q; else q5 = q;
        }
    }

    // Phase 0: solve (wave 0 only) — runs under the kq load latency.
    if (tid < 64) {
        int lane = tid;
        unsigned int h[16], s = 0;
        #pragma unroll
        for (int i = 0; i < 16; i++) { h[i] = hist[lane * 16 + i]; s += h[i]; }
        unsigned int inc = s;
        #pragma unroll
        for (int d = 1; d < 64; d <<= 1) {
            unsigned int t = __shfl_up(inc, d);
            if (lane >= d) inc += t;
        }
        unsigned int excl = inc - s;
        bool cross = (excl < LO_COUNT) && (excl + s >= LO_COUNT);
        unsigned long long m = __ballot(cross);
        if (m) {
            int cl = __ffsll((long long)m) - 1;
            if (lane == cl) {
                unsigned int c = excl; int ks = K_STEPS - 1;
                for (int i = 0; i < 16; i++) { c += h[i]; if (c >= LO_COUNT) { ks = lane * 16 + i; break; } }
                ksS = ks;
            }
        } else if (lane == 0) ksS = K_STEPS - 1;
    }
    __syncthreads();
    int ks = ksS;

    // Phase 1: binarize the held chunks -> 16-bit masks -> LDS.
    // Out-of-plane rows masked to 0 AFTER the compares.
    unsigned short* Tt16 = (unsigned short*)Tt;
    #pragma unroll
    for (int i = 0; i < 6; i++) {
        uint4 q = (i == 0) ? q0 : (i == 1) ? q1 : (i == 2) ? q2
                : (i == 3) ? q3 : (i == 4) ? q4 : q5;
        int ch = tid + 256 * i;
        int r = ch >> 6;
        int pr = y0 - 4 + r;
        unsigned int m = 0u;
        unsigned int wv;
        wv = q.x;
        m |= (unsigned)((wv & 0xffu) <= (unsigned)ks)
           | ((unsigned)(((wv >> 8) & 0xffu) <= (unsigned)ks) << 1)
           | ((unsigned)(((wv >> 16) & 0xffu) <= (unsigned)ks) << 2)
           | ((unsigned)((wv >> 24) <= (unsigned)ks) << 3);
        wv = q.y;
        m |= ((unsigned)((wv & 0xffu) <= (unsigned)ks) << 4)
           | ((unsigned)(((wv >> 8) & 0xffu) <= (unsigned)ks) << 5)
           | ((unsigned)(((wv >> 16) & 0xffu) <= (unsigned)ks) << 6)
           | ((unsigned)((wv >> 24) <= (unsigned)ks) << 7);
        wv = q.z;
        m |= ((unsigned)((wv & 0xffu) <= (unsigned)ks) << 8)
           | ((unsigned)(((wv >> 8) & 0xffu) <= (unsigned)ks) << 9)
           | ((unsigned)(((wv >> 16) & 0xffu) <= (unsigned)ks) << 10)
           | ((unsigned)((wv >> 24) <= (unsigned)ks) << 11);
        wv = q.w;
        m |= ((unsigned)((wv & 0xffu) <= (unsigned)ks) << 12)
           | ((unsigned)(((wv >> 8) & 0xffu) <= (unsigned)ks) << 13)
           | ((unsigned)(((wv >> 16) & 0xffu) <= (unsigned)ks) << 14)
           | ((unsigned)((wv >> 24) <= (unsigned)ks) << 15);
        if ((unsigned)pr >= 1024u) m = 0u;     // halo rows are OUTSIDE: thr=0
        Tt16[ch] = (unsigned short)m;
    }
    __syncthreads();

    // Phase 2: vertical OR of 5 thr rows (20 rows x 16 words = 320)
    for (int i = tid; i < 320; i += 256) {
        int vr = i >> 4, wc = i & 15;
        int b = vr * 16 + wc;
        Vv[i] = Tt[b] | Tt[b + 16] | Tt[b + 32] | Tt[b + 48] | Tt[b + 64];
    }
    __syncthreads();

    // Phase 3: horizontal dilate; rows outside the plane forced to all-ones
    // (erode identity — erosion ignores out-of-image rows).
    for (int i = tid; i < 320; i += 256) {
        int vr = i >> 4, wc = i & 15;
        int pr = y0 - 2 + vr;
        if ((unsigned)pr >= 1024u) { Dd[i] = ~0ull; continue; }
        unsigned long long Vc = Vv[i];
        unsigned long long Vl = (wc > 0)  ? Vv[i - 1] : 0ull;
        unsigned long long Vr = (wc < 15) ? Vv[i + 1] : 0ull;
        Dd[i] = Vc
            | (Vc << 1) | (Vl >> 63)
            | (Vc << 2) | (Vl >> 62)
            | (Vc >> 1) | (Vr << 63)
            | (Vc >> 2) | (Vr << 62);
    }
    __syncthreads();

    // Phase 4: vertical AND of 5 dilated rows (16 x 16 = 256)
    {
        int wr = tid >> 4, wc = tid & 15;
        int b = wr * 16 + wc;
        Ww[tid] = Dd[b] & Dd[b + 16] & Dd[b + 32] & Dd[b + 48] & Dd[b + 64];
    }
    __syncthreads();

    // Phase 5: horizontal erode (outside cols = 1)
    {
        int wc = tid & 15;
        unsigned long long Wc = Ww[tid];
        unsigned long long Wl = (wc > 0)  ? Ww[tid - 1] : ~0ull;
        unsigned long long Wr = (wc < 15) ? Ww[tid + 1] : ~0ull;
        Ff[tid] = Wc
            & ((Wc << 1) | (Wl >> 63))
            & ((Wc << 2) | (Wl >> 62))
            & ((Wc >> 1) | (Wr << 63))
            & ((Wc >> 2) | (Wr << 62));
    }
    __syncthreads();

    // Phase 6: unpack to f32, nontemporal coalesced 16B stores
    for (int i = 0; i < PT_ROWS; i++) {
        unsigned long long wd = Ff[i * 16 + (tid >> 4)];
        int sh = (tid & 15) * 4;
        fx4 f;
        f.x = (float)((wd >> sh) & 1ull);
        f.y = (float)((wd >> (sh + 1)) & 1ull);
        f.z = (float)((wd >> (sh + 2)) & 1ull);
        f.w = (float)((wd >> (sh + 3)) & 1ull);
        fx4* dst = (fx4*)(out + (size_t)p * 1048576 + (size_t)(y0 + i) * 1024) + tid;
        __builtin_nontemporal_store(f, dst);
    }
}

extern "C" void kernel_launch(void* const* d_in, const int* in_sizes, int n_in,
                              void* d_out, int out_size, void* d_ws, size_t ws_size,
                              hipStream_t stream) {
    const float4* x4 = (const float4*)d_in[0];
    const float*  bk = (const float*)d_in[1];
    float* out = (float*)d_out;

    char* ws = (char*)d_ws;
    unsigned int*   hist = (unsigned int*)(ws + OFF_HIST);
    unsigned short* kq16 = (unsigned short*)(ws + OFF_KQ);
    const unsigned char* kqb = (const unsigned char*)(ws + OFF_KQ);

    (void)hipMemsetAsync(hist, 0, (K_STEPS + 1) * sizeof(unsigned int), stream);

    dim3 g1(1024 / R_TILE, 32);
    k_pass1<<<g1, 256, 0, stream>>>(x4, bk, hist, kq16);

    dim3 g2(1024 / PT_ROWS, 32);
    k_post<<<g2, 256, 0, stream>>>(kqb, hist, out);
}

// Round 9
// 288.714 us; speedup vs baseline: 1.0143x; 1.0012x over previous
//
#include <hip/hip_runtime.h>

// 32 planes of 1024x1024 f32: 5x5 box blur (SAME, zero-pad) -> data-dependent
// threshold (quantile over exact f32 cascade T[k]=T[k-1]-0.0005f) -> binarize
// -> morphological close (5x5 dilate, 5x5 erode) -> f32 0/1 output.
//
// Round 13: pass1 row history lives in a per-thread LDS circular buffer.
// Rounds 3/6/8 showed the register allocator sinks or spills ANY multi-row
// register pipeline (VGPR pinned at 32, loads sunk to uses), and the
// two-global-stream variant re-fetches the departing row (FETCH 149.5MB).
// New scheme: one global load per iter (row y+3); converted u32 columns are
// ds_write'n to hrA[slot][tid] (5 slots x 256 x 16B, per-thread private ->
// no barriers, conflict-free b128); the departing row is ds_read from the
// same slot (S(y-2)==S(y+3) mod 5, read-then-overwrite, must-alias so the
// compiler keeps order). One cvt4 per row instead of two.
// LDS ~28.9KB -> 5 blocks/CU; __launch_bounds__(256,5).
// k_post unchanged (round-12-verified).

#define K_STEPS 1024
#define LO_COUNT 28185723u     // ceil(0.84 * 2^25)
#define R_TILE 16              // pass1 rows per block -> 64x32 = 2048 blocks
#define PT_ROWS 16             // post rows per block  -> 64x32 = 2048 blocks

// ws: (unused)[4096] @0 ; hist[1025] @4096 ; kq u8[2^25] @16384 (32MB)
#define OFF_HIST 4096
#define OFF_KQ   16384

typedef float  fx4 __attribute__((ext_vector_type(4)));

struct TTable { float v[K_STEPS]; };
static constexpr TTable make_T() {
    TTable t{};
    float th = 0.5f;                          // TH1_INIT; exact f32 cascade
    for (int k = 0; k < K_STEPS; k++) { t.v[k] = th; th = th - 0.0005f; }
    return t;
}
__device__ constexpr TTable Tc = make_T();

__device__ __forceinline__ uint4 cvt4(float4 f) {
    // x in [0,1) is a multiple of 2^-23 -> x*2^23 is an exact integer in f32
    return make_uint4((unsigned int)(f.x * 8388608.0f),
                      (unsigned int)(f.y * 8388608.0f),
                      (unsigned int)(f.z * 8388608.0f),
                      (unsigned int)(f.w * 8388608.0f));
}

// smallest k with s >= Us[k] (Us non-increasing staircase, ~104857.6 s-units
// per step). Cascade drift <= 1024*2^-25 = 0.061 step; f32 guess arithmetic
// (values < 2^28, fma) <= ~2e-4 step. For s in [U[k],U[k-1]): g in
// (k-1.062, k+0.062]; +0.5 bias -> g' in (k-0.562, k+0.562] -> floor(g') in
// {k-1, k} -> window {lo, lo+1} contains k; indicator sum is exact:
//   lo=k-1: s<Us[k-1] (+1), s>=Us[k] (+0) -> k.   lo=k: both >= -> k.
// s >= U0 (k=0): g' < 0.562 -> lo=0, indicators 0 -> 0. s=0: g'~1000.5 ->
// lo=1000, U[1000]=1 (+1), U[1001]=0 (+0) -> 1001 (= first zero bin).
__device__ __forceinline__ int find_ki(const unsigned int* __restrict__ Us,
                                       float gbias, unsigned int s) {
    float g = fmaf(-(float)s, 9.5367432e-6f, gbias);   // gbias = U0*inv + 0.5
    int lo = (int)g;
    lo = max(0, min(1022, lo));
    unsigned int a0 = Us[lo], a1 = Us[lo + 1];
    return lo + (int)(s < a0) + (int)(s < a1);
}

// Pass 1: 16-row strip per block. Thread t owns cols 4t..4t+3 running sums
// (rows y-2..y+2) with the 5-row u32 history in a PRIVATE LDS circular
// buffer; neighbor sums from lane t+1 via __shfl_down; edge lanes
// (wlane==63) keep a private neighbor stream (tid 255 wraps to cols 0..3).
// Outputs cols 4t+2..4t+5 (tid 255: 1022,1023,0,1). Per iteration: one
// global load (row y+3) -> compute from current sums -> retire (ds_read old
// slot, ds_write new row into it, update sums). k==0 (~50% of px) counted
// in a register; LDS atomics only for k>0. Aligned u32 kq stores via shfl.
__global__ __launch_bounds__(256, 5) void
k_pass1(const float4* __restrict__ x4, const float* __restrict__ bk,
        unsigned int* __restrict__ hist, unsigned short* __restrict__ kq16) {
    __shared__ unsigned int Us[K_STEPS];
    __shared__ unsigned int lh[K_STEPS + 1];
    __shared__ uint4 hrA[5][256];               // per-thread 5-row history
    __shared__ uint4 hrB[5][4];                 // edge-lane (per-wave) history
    int tid = threadIdx.x;
    int p = blockIdx.y, y0 = blockIdx.x * R_TILE;
    int wlane = tid & 63;
    int w = tid >> 6;

    {   // Build U table: U[k] = min{u : u*c > T[k]} exactly.
        // u < 2^27, c = w*2^-23 (24-bit mantissa) -> u*c exact in double.
        double c = (double)bk[0] * (1.0 / 8388608.0);
        #pragma unroll
        for (int i = 0; i < 4; i++) {
            int k = tid + 256 * i;
            double T = (double)Tc.v[k];
            unsigned int u = 0u;
            if (T >= 0.0) {
                u = (unsigned int)(floor(T / c) + 1.0);
                while (u > 0u && (double)(u - 1u) * c > T) u--;
                while (!((double)u * c > T)) u++;
            }
            Us[k] = u;
        }
    }
    for (int i = tid; i < K_STEPS + 1; i += 256) lh[i] = 0u;
    __syncthreads();
    float gbias = fmaf((float)Us[0], 9.5367432e-6f, 0.5f);

    const float4* pf = x4 + (size_t)p * 262144;   // 256 float4 per row
    int tB = (tid < 255) ? tid + 1 : 0;
    const uint4 z4 = make_uint4(0u, 0u, 0u, 0u);
    bool edge = (wlane == 63);

    // slot(r) = (r+5) % 5; s0 = slot(y0-2) = slot(y0+3)
    int s0 = (y0 + 3) % 5;

    unsigned int cs0 = 0, cs1 = 0, cs2 = 0, cs3 = 0;
    unsigned int cb0 = 0, cb1 = 0, cb2 = 0, cb3 = 0;  // edge lanes only
    {   // prologue: rows y0-2 .. y0+2 -> sums + history slots
        float4 ra[5], rb[5];
        #pragma unroll
        for (int i = 0; i < 5; i++) {
            int yy = y0 - 2 + i, yc = min(max(yy, 0), 1023);
            ra[i] = pf[yc * 256 + tid];
            if (edge) rb[i] = pf[yc * 256 + tB];
        }
        #pragma unroll
        for (int i = 0; i < 5; i++) {
            int sl = s0 + i; if (sl >= 5) sl -= 5;
            bool v = (unsigned)(y0 - 2 + i) < 1024u;
            uint4 a = v ? cvt4(ra[i]) : z4;
            cs0 += a.x; cs1 += a.y; cs2 += a.z; cs3 += a.w;
            hrA[sl][tid] = a;
            if (edge) {
                uint4 b = v ? cvt4(rb[i]) : z4;
                cb0 += b.x; cb1 += b.y; cb2 += b.z; cb3 += b.w;
                hrB[sl][w] = b;
            }
        }
    }

    unsigned int cnt0 = 0;
    int sl = s0;
    #pragma unroll 4
    for (int iy = 0; iy < R_TILE; iy++) {
        int y = y0 + iy;

        // (1) ISSUE the single incoming-row load (clamped address).
        int yn = min(y + 3, 1023);
        float4 Na = pf[yn * 256 + tid];
        float4 Nb;
        if (edge) Nb = pf[yn * 256 + tB];

        // (2) COMPUTE from current running sums.
        unsigned int nc0 = __shfl_down(cs0, 1);
        unsigned int nc1 = __shfl_down(cs1, 1);
        unsigned int nc2 = __shfl_down(cs2, 1);
        unsigned int nc3 = __shfl_down(cs3, 1);
        if (edge) { nc0 = cb0; nc1 = cb1; nc2 = cb2; nc3 = cb3; }

        unsigned int m123 = cs1 + cs2 + cs3;
        unsigned int h45  = nc0 + nc1;
        unsigned int v0, v1, v2, v3;
        if (tid != 255) {
            v0 = cs0 + m123 + nc0;                // col 4t+2
            v1 = m123 + h45;                      // col 4t+3
            v2 = cs2 + cs3 + h45 + nc2;           // col 4t+4
            v3 = cs3 + h45 + nc2 + nc3;           // col 4t+5
        } else {
            v0 = cs0 + m123;                      // col 1022 (cols 1020..1023)
            v1 = m123;                            // col 1023 (cols 1021..1023)
            v2 = h45 + nc2;                       // col 0    (cols 0..2)
            v3 = h45 + nc2 + nc3;                 // col 1    (cols 0..3)
        }

        int k0 = find_ki(Us, gbias, v0);
        int k1 = find_ki(Us, gbias, v1);
        int k2 = find_ki(Us, gbias, v2);
        int k3 = find_ki(Us, gbias, v3);
        cnt0 += (unsigned)(k0 == 0) + (unsigned)(k1 == 0)
              + (unsigned)(k2 == 0) + (unsigned)(k3 == 0);
        if (k0 > 0) atomicAdd(&lh[k0], 1u);
        if (k1 > 0) atomicAdd(&lh[k1], 1u);
        if (k2 > 0) atomicAdd(&lh[k2], 1u);
        if (k3 > 0) atomicAdd(&lh[k3], 1u);

        // pack + aligned coalesced store. Word w = cols 4w..4w+3.
        // word(t+1) = pb(t) | pa(t+1)<<16 (wlane<63 via shfl); words 64w:
        // low half = pb of wlane==63 (u16 at 2t+2; tid 255 -> u16 0),
        // high half = pa of wlane==0 (u16 at 2t+1).
        unsigned int pa = (unsigned)min(k0, 255) | ((unsigned)min(k1, 255) << 8);
        unsigned int pb = (unsigned)min(k2, 255) | ((unsigned)min(k3, 255) << 8);
        unsigned int paN = __shfl_down(pa, 1);
        size_t rb = ((size_t)p * 1024 + (size_t)y) * 512;   // u16 units
        if (wlane < 63) {
            ((unsigned int*)(kq16 + rb))[tid + 1] = pb | (paN << 16);
        } else {
            kq16[rb + ((tid < 255) ? (unsigned)(2 * tid + 2) : 0u)] =
                (unsigned short)pb;
        }
        if (wlane == 0) kq16[rb + 2 * tid + 1] = (unsigned short)pa;

        // (3) RETIRE: old row (y-2) out of LDS slot, new row (y+3) into the
        // SAME slot (slot(y-2)==slot(y+3) mod 5; read precedes overwrite).
        {
            bool vn = (unsigned)(y + 3) < 1024u;
            uint4 oa = hrA[sl][tid];
            uint4 na = vn ? cvt4(Na) : z4;
            hrA[sl][tid] = na;
            cs0 += na.x - oa.x; cs1 += na.y - oa.y;
            cs2 += na.z - oa.z; cs3 += na.w - oa.w;
            if (edge) {
                uint4 ob = hrB[sl][w];
                uint4 nb = vn ? cvt4(Nb) : z4;
                hrB[sl][w] = nb;
                cb0 += nb.x - ob.x; cb1 += nb.y - ob.y;
                cb2 += nb.z - ob.z; cb3 += nb.w - ob.w;
            }
        }
        sl++; if (sl == 5) sl = 0;
    }

    #pragma unroll
    for (int d = 32; d > 0; d >>= 1) cnt0 += __shfl_down(cnt0, d);
    if ((tid & 63) == 0 && cnt0) atomicAdd(&lh[0], cnt0);
    __syncthreads();
    for (int i = tid; i < K_STEPS + 1; i += 256) {
        unsigned int c = lh[i];
        if (c) atomicAdd(&hist[i], c);
    }
}

// Fused post: in-block solve -> binarize (k<=ks) -> dilate -> erode -> f32
// unpack. 16-row tile per block, bit-packed intermediates in LDS. kq loads
// hoisted ABOVE the solve so hist-read latency and kq-read latency overlap.
// Out-of-plane rows are masked to 0 AFTER the byte compares (a zero byte
// binarizes to 1 — round-7 bug).
// Loop 2 of the reference (frac > 0.86) cannot trigger: it needs a single
// 0.0005-wide bin holding >= 671089 px; max possible ~115k.
__global__ __launch_bounds__(256, 6) void
k_post(const unsigned char* __restrict__ kqb, const unsigned int* __restrict__ hist,
       float* __restrict__ out) {
    __shared__ unsigned long long Tt[24 * 16];  // thr rows y0-4 .. y0+19
    __shared__ unsigned long long Vv[20 * 16];  // vertical OR, rows y0-2 .. y0+17
    __shared__ unsigned long long Dd[20 * 16];  // dilated,     rows y0-2 .. y0+17
    __shared__ unsigned long long Ww[16 * 16];  // vertical AND, rows y0 .. y0+15
    __shared__ unsigned long long Ff[16 * 16];  // closed bits
    __shared__ int ksS;

    int tid = threadIdx.x;
    int p = blockIdx.y, y0 = blockIdx.x * PT_ROWS;

    // Phase -1: ISSUE all six kq chunk loads (independent of ks).
    const unsigned char* kp = kqb + (size_t)p * 1048576;
    uint4 q0, q1, q2, q3, q4, q5;
    {
        const uint4 zq = make_uint4(0u, 0u, 0u, 0u);
        #pragma unroll
        for (int i = 0; i < 6; i++) {
            int ch = tid + 256 * i;         // 0..1535
            int r = ch >> 6, cc = ch & 63;
            int pr = y0 - 4 + r;
            uint4 q = zq;
            if ((unsigned)pr < 1024u)
                q = ((const uint4*)(kp + (size_t)pr * 1024))[cc];
            if (i == 0) q0 = q; else if (i == 1) q1 = q;
            else if (i == 2) q2 = q; else if (i == 3) q3 = q;
            else if (i == 4) q4 = q; else q5 = q;
        }
    }

    // Phase 0: solve (wave 0 only) — runs under the kq load latency.
    if (tid < 64) {
        int lane = tid;
        unsigned int h[16], s = 0;
        #pragma unroll
        for (int i = 0; i < 16; i++) { h[i] = hist[lane * 16 + i]; s += h[i]; }
        unsigned int inc = s;
        #pragma unroll
        for (int d = 1; d < 64; d <<= 1) {
            unsigned int t = __shfl_up(inc, d);
            if (lane >= d) inc += t;
        }
        unsigned int excl = inc - s;
        bool cross = (excl < LO_COUNT) && (excl + s >= LO_COUNT);
        unsigned long long m = __ballot(cross);
        if (m) {
            int cl = __ffsll((long long)m) - 1;
            if (lane == cl) {
                unsigned int c = excl; int ks = K_STEPS - 1;
                for (int i = 0; i < 16; i++) { c += h[i]; if (c >= LO_COUNT) { ks = lane * 16 + i; break; } }
                ksS = ks;
            }
        } else if (lane == 0) ksS = K_STEPS - 1;
    }
    __syncthreads();
    int ks = ksS;

    // Phase 1: binarize the held chunks -> 16-bit masks -> LDS.
    // Out-of-plane rows masked to 0 AFTER the compares.
    unsigned short* Tt16 = (unsigned short*)Tt;
    #pragma unroll
    for (int i = 0; i < 6; i++) {
        uint4 q = (i == 0) ? q0 : (i == 1) ? q1 : (i == 2) ? q2
                : (i == 3) ? q3 : (i == 4) ? q4 : q5;
        int ch = tid + 256 * i;
        int r = ch >> 6;
        int pr = y0 - 4 + r;
        unsigned int m = 0u;
        unsigned int wv;
        wv = q.x;
        m |= (unsigned)((wv & 0xffu) <= (unsigned)ks)
           | ((unsigned)(((wv >> 8) & 0xffu) <= (unsigned)ks) << 1)
           | ((unsigned)(((wv >> 16) & 0xffu) <= (unsigned)ks) << 2)
           | ((unsigned)((wv >> 24) <= (unsigned)ks) << 3);
        wv = q.y;
        m |= ((unsigned)((wv & 0xffu) <= (unsigned)ks) << 4)
           | ((unsigned)(((wv >> 8) & 0xffu) <= (unsigned)ks) << 5)
           | ((unsigned)(((wv >> 16) & 0xffu) <= (unsigned)ks) << 6)
           | ((unsigned)((wv >> 24) <= (unsigned)ks) << 7);
        wv = q.z;
        m |= ((unsigned)((wv & 0xffu) <= (unsigned)ks) << 8)
           | ((unsigned)(((wv >> 8) & 0xffu) <= (unsigned)ks) << 9)
           | ((unsigned)(((wv >> 16) & 0xffu) <= (unsigned)ks) << 10)
           | ((unsigned)((wv >> 24) <= (unsigned)ks) << 11);
        wv = q.w;
        m |= ((unsigned)((wv & 0xffu) <= (unsigned)ks) << 12)
           | ((unsigned)(((wv >> 8) & 0xffu) <= (unsigned)ks) << 13)
           | ((unsigned)(((wv >> 16) & 0xffu) <= (unsigned)ks) << 14)
           | ((unsigned)((wv >> 24) <= (unsigned)ks) << 15);
        if ((unsigned)pr >= 1024u) m = 0u;     // halo rows are OUTSIDE: thr=0
        Tt16[ch] = (unsigned short)m;
    }
    __syncthreads();

    // Phase 2: vertical OR of 5 thr rows (20 rows x 16 words = 320)
    for (int i = tid; i < 320; i += 256) {
        int vr = i >> 4, wc = i & 15;
        int b = vr * 16 + wc;
        Vv[i] = Tt[b] | Tt[b + 16] | Tt[b + 32] | Tt[b + 48] | Tt[b + 64];
    }
    __syncthreads();

    // Phase 3: horizontal dilate; rows outside the plane forced to all-ones
    // (erode identity — erosion ignores out-of-image rows).
    for (int i = tid; i < 320; i += 256) {
        int vr = i >> 4, wc = i & 15;
        int pr = y0 - 2 + vr;
        if ((unsigned)pr >= 1024u) { Dd[i] = ~0ull; continue; }
        unsigned long long Vc = Vv[i];
        unsigned long long Vl = (wc > 0)  ? Vv[i - 1] : 0ull;
        unsigned long long Vr = (wc < 15) ? Vv[i + 1] : 0ull;
        Dd[i] = Vc
            | (Vc << 1) | (Vl >> 63)
            | (Vc << 2) | (Vl >> 62)
            | (Vc >> 1) | (Vr << 63)
            | (Vc >> 2) | (Vr << 62);
    }
    __syncthreads();

    // Phase 4: vertical AND of 5 dilated rows (16 x 16 = 256)
    {
        int wr = tid >> 4, wc = tid & 15;
        int b = wr * 16 + wc;
        Ww[tid] = Dd[b] & Dd[b + 16] & Dd[b + 32] & Dd[b + 48] & Dd[b + 64];
    }
    __syncthreads();

    // Phase 5: horizontal erode (outside cols = 1)
    {
        int wc = tid & 15;
        unsigned long long Wc = Ww[tid];
        unsigned long long Wl = (wc > 0)  ? Ww[tid - 1] : ~0ull;
        unsigned long long Wr = (wc < 15) ? Ww[tid + 1] : ~0ull;
        Ff[tid] = Wc
            & ((Wc << 1) | (Wl >> 63))
            & ((Wc << 2) | (Wl >> 62))
            & ((Wc >> 1) | (Wr << 63))
            & ((Wc >> 2) | (Wr << 62));
    }
    __syncthreads();

    // Phase 6: unpack to f32, nontemporal coalesced 16B stores
    for (int i = 0; i < PT_ROWS; i++) {
        unsigned long long wd = Ff[i * 16 + (tid >> 4)];
        int sh = (tid & 15) * 4;
        fx4 f;
        f.x = (float)((wd >> sh) & 1ull);
        f.y = (float)((wd >> (sh + 1)) & 1ull);
        f.z = (float)((wd >> (sh + 2)) & 1ull);
        f.w = (float)((wd >> (sh + 3)) & 1ull);
        fx4* dst = (fx4*)(out + (size_t)p * 1048576 + (size_t)(y0 + i) * 1024) + tid;
        __builtin_nontemporal_store(f, dst);
    }
}

extern "C" void kernel_launch(void* const* d_in, const int* in_sizes, int n_in,
                              void* d_out, int out_size, void* d_ws, size_t ws_size,
                              hipStream_t stream) {
    const float4* x4 = (const float4*)d_in[0];
    const float*  bk = (const float*)d_in[1];
    float* out = (float*)d_out;

    char* ws = (char*)d_ws;
    unsigned int*   hist = (unsigned int*)(ws + OFF_HIST);
    unsigned short* kq16 = (unsigned short*)(ws + OFF_KQ);
    const unsigned char* kqb = (const unsigned char*)(ws + OFF_KQ);

    (void)hipMemsetAsync(hist, 0, (K_STEPS + 1) * sizeof(unsigned int), stream);

    dim3 g1(1024 / R_TILE, 32);
    k_pass1<<<g1, 256, 0, stream>>>(x4, bk, hist, kq16);

    dim3 g2(1024 / PT_ROWS, 32);
    k_post<<<g2, 256, 0, stream>>>(kqb, hist, out);
}